// Round 7
// baseline (270.786 us; speedup 1.0000x reference)
//
#include <hip/hip_runtime.h>
#include <hip/hip_bf16.h>

// Problem constants
#define L_SEQ   2048
#define DMODEL  1024
#define NH      16
#define HD      64
#define MROWS   8192          // B*L
// reference: logits = (Q.K) * 1/sqrt(H); fold 0.25*log2(e) into Q -> base-2 softmax
#define QSC     0.360673760222f   // 0.25 * log2(e)
#define NEG2    -2.0e7f           // mask in base-2 domain; exp2 -> exactly 0

typedef float  f32x4 __attribute__((ext_vector_type(4)));
typedef short  s16x8 __attribute__((ext_vector_type(8)));

// round-to-nearest-even f32 -> bf16 bits
__device__ __forceinline__ unsigned short f2bf(float f) {
    union { float f; unsigned u; } v; v.f = f;
    unsigned r = (v.u + 0x7FFFu + ((v.u >> 16) & 1u)) >> 16;
    return (unsigned short)r;
}

__device__ __forceinline__ float fexp2(float x) {
#if __has_builtin(__builtin_amdgcn_exp2f)
    return __builtin_amdgcn_exp2f(x);
#else
    return __expf(x * 0.6931471805599453f);
#endif
}

// pack trunc-bf16(a) low | trunc-bf16(b) high — single v_perm_b32
__device__ __forceinline__ unsigned pk2(float a, float b) {
    union { float f; unsigned u; } ua, ub; ua.f = a; ub.f = b;
    return __builtin_amdgcn_perm(ub.u, ua.u, 0x07060302u);
}

__device__ __forceinline__ void gl_lds16(const void* g, void* l) {
    __builtin_amdgcn_global_load_lds(
        (const __attribute__((address_space(1))) unsigned int*)g,
        (__attribute__((address_space(3))) unsigned int*)l, 16, 0, 0);
}

// ---------------- fused fp32 -> bf16 conversion (X + 3 W's, one dispatch) ----------------
__global__ __launch_bounds__(256) void cvt_all(const float* __restrict__ X,
                                               const float* __restrict__ W0,
                                               const float* __restrict__ W1,
                                               const float* __restrict__ W2,
                                               unsigned short* __restrict__ Xb,
                                               unsigned short* __restrict__ Wb) {
    const int bx = blockIdx.x, tid = threadIdx.x;
    const float* src; unsigned short* dst; int i;
    if (bx < 8192) {                       // X: 8M elems = 2M float4
        src = X; dst = Xb; i = bx * 256 + tid;
    } else {                               // W's: 1M elems = 256K float4 each
        int r = bx - 8192; const int wsel = r >> 10; r &= 1023;
        src = (wsel == 0) ? W0 : (wsel == 1) ? W1 : W2;
        dst = Wb + (size_t)wsel * (DMODEL * DMODEL);
        i = r * 256 + tid;
    }
    float4 v = ((const float4*)src)[i];
    ushort4 o;
    o.x = f2bf(v.x); o.y = f2bf(v.y); o.z = f2bf(v.z); o.w = f2bf(v.w);
    ((ushort4*)dst)[i] = o;
}

// ---------------- QKV projection GEMM: Y = X @ W^T + b ----------------
// BK=64, xor-swizzled LDS, swapped operands, head-major output Y[z][bh][sl][hd].
// Q (z==0) pre-scaled by QSC.
__global__ __launch_bounds__(256, 2) void qkv_gemm(
        const unsigned short* __restrict__ Xb,   // [8192][1024] bf16
        const unsigned short* __restrict__ Wb,   // [3][1024][1024] bf16
        const float* __restrict__ bq, const float* __restrict__ bk_,
        const float* __restrict__ bv,
        unsigned short* __restrict__ Yb) {       // [3][B*H][L][HD] bf16
    __shared__ unsigned short As[128 * 64];
    __shared__ unsigned short Bs[128 * 64];

    const int tid = threadIdx.x;
    const int w = tid >> 6, l = tid & 63, q = l >> 4, t = l & 15;
    const int mw = w >> 1, nw = w & 1;
    const int z = blockIdx.z;
    const int rowM0 = blockIdx.x * 128;
    const int colN0 = blockIdx.y * 128;

    const unsigned short* W = Wb + (size_t)z * (DMODEL * DMODEL);
    unsigned short* Y = Yb + (size_t)z * ((size_t)MROWS * DMODEL);
    const float* bias = (z == 0) ? bq : (z == 1) ? bk_ : bv;
    const float osc = (z == 0) ? QSC : 1.0f;

    f32x4 acc[4][4] = {};   // [in][jm]

    const int srow8 = l >> 3;              // 0..7
    const int sch_g = ((l & 7) ^ srow8) * 8;

    const int coff0 = ((q) ^ (t & 7)) * 8;
    const int coff1 = ((4 + q) ^ (t & 7)) * 8;

    for (int k0 = 0; k0 < DMODEL; k0 += 64) {
        #pragma unroll
        for (int r = 0; r < 4; ++r) {
            const int row = w * 32 + r * 8;
            gl_lds16(Xb + (size_t)(rowM0 + row + srow8) * DMODEL + k0 + sch_g, As + row * 64);
            gl_lds16(W  + (size_t)(colN0 + row + srow8) * DMODEL + k0 + sch_g, Bs + row * 64);
        }
        __syncthreads();
        #pragma unroll
        for (int ks = 0; ks < 2; ++ks) {
            const int co = ks ? coff1 : coff0;
            s16x8 a[4], b[4];
            #pragma unroll
            for (int i = 0; i < 4; ++i) {
                a[i] = *(const s16x8*)&As[(mw * 64 + i * 16 + t) * 64 + co];
                b[i] = *(const s16x8*)&Bs[(nw * 64 + i * 16 + t) * 64 + co];
            }
            #pragma unroll
            for (int in = 0; in < 4; ++in)
                #pragma unroll
                for (int jm = 0; jm < 4; ++jm)
                    acc[in][jm] = __builtin_amdgcn_mfma_f32_16x16x32_bf16(b[in], a[jm], acc[in][jm], 0, 0, 0);
        }
        __syncthreads();
    }

    const int bb = rowM0 >> 11;            // batch
    #pragma unroll
    for (int in = 0; in < 4; ++in) {
        const int ncol = colN0 + nw * 64 + in * 16 + q * 4;
        const int hh = ncol >> 6, hd = ncol & 63;
        const float4 b4 = *(const float4*)&bias[ncol];
        unsigned short* Yh = Y + ((size_t)(bb * NH + hh) * L_SEQ) * HD + hd;
        #pragma unroll
        for (int jm = 0; jm < 4; ++jm) {
            const int sl = (rowM0 & 2047) + mw * 64 + jm * 16 + t;
            unsigned lo = ((unsigned)f2bf((acc[in][jm][0] + b4.x) * osc)) |
                          ((unsigned)f2bf((acc[in][jm][1] + b4.y) * osc) << 16);
            unsigned hi = ((unsigned)f2bf((acc[in][jm][2] + b4.z) * osc)) |
                          ((unsigned)f2bf((acc[in][jm][3] + b4.w) * osc) << 16);
            uint2 o; o.x = lo; o.y = hi;
            *(uint2*)&Yh[(size_t)sl * HD] = o;
        }
    }
}

// ---------------- flash attention fwd (causal), S^T, base-2, NO running max ----------------
// One 128-row q-tile per block; 1024 blocks (4/CU), heavy-first (qt descending in
// dispatch order = LPT greedy), XCD-pinned bh for K/V L2 residency.
// Prefetch pipeline with 1 barrier/chunk. Q/K/V head-major [B*H][L][64] bf16.
__global__ __launch_bounds__(256, 4) void attn_fwd(
        const unsigned short* __restrict__ Qb,
        const unsigned short* __restrict__ Kb,
        const unsigned short* __restrict__ Vb,
        float* __restrict__ out) {
    __shared__ __align__(16) unsigned short Ks[2][64 * 64];   // xor-swizzled K tiles
    __shared__ __align__(16) unsigned short Vt[2][64 * 72];   // slot-permuted V^T tiles

    const int tid = threadIdx.x;
    const int w = tid >> 6, l = tid & 63, q = l >> 4, t = l & 15;

    const int lin = blockIdx.x;          // 0..1023
    const int xcd = lin & 7;
    const int bhg = (lin >> 3) & 7;      // 0..7
    const int qt  = 15 - (lin >> 6);     // heavy tiles first
    const int bh  = bhg * 8 + xcd;       // bh & 7 == xcd -> L2-resident K/V per XCD
    const int b = bh >> 4, h = bh & 15;
    const size_t base = (size_t)bh * (L_SEQ * HD);

    const int Q0 = qt * 128;
    const int n = 2 * qt + 2;            // 64-j chunks
    const int m_min = Q0 + w * 32;       // wave's lowest m row

    // V staging: thread covers j-pair {2jp,2jp+1}, d-chunk d8
    const int d8 = tid >> 5, jp = tid & 31;
    const int vslot = ((jp >> 4) << 5) | (((jp >> 1) & 3) << 3) | (((jp >> 3) & 1) << 2) | ((jp & 1) << 1);
    // K async staging (xor-swizzle)
    const int krow_in = l >> 3;
    const int kchunk_g = (l & 7) ^ krow_in;

    int kaddr[4][2], vaddr[4][2];
    #pragma unroll
    for (int nt = 0; nt < 4; ++nt)
        #pragma unroll
        for (int ks = 0; ks < 2; ++ks) {
            kaddr[nt][ks] = (nt * 16 + t) * 64 + (((ks * 4 + q) ^ (t & 7)) * 8);
            vaddr[nt][ks] = (nt * 16 + t) * 72 + ks * 32 + q * 8;
        }

    s16x8 vone;
    #pragma unroll
    for (int i = 0; i < 8; ++i) vone[i] = (short)0x3F80;   // bf16 1.0

    auto issueK = [&](int jbase, unsigned short* dst) {
        #pragma unroll
        for (int r = 0; r < 2; ++r) {
            const int rb = r * 4 + w;
            gl_lds16(Kb + base + (size_t)(jbase + rb * 8 + krow_in) * HD + kchunk_g * 8,
                     dst + rb * 512);
        }
    };
    auto loadV = [&](int jbase, uint4& a, uint4& bb2) {
        const unsigned short* vp = Vb + base + (size_t)(jbase + 2 * jp) * HD + d8 * 8;
        a   = *(const uint4*)vp;
        bb2 = *(const uint4*)(vp + HD);
    };
    auto writeV = [&](const uint4& a, const uint4& bb2, unsigned short* dst) {
        const unsigned* u0 = (const unsigned*)&a;
        const unsigned* u1 = (const unsigned*)&bb2;
        #pragma unroll
        for (int i = 0; i < 4; ++i) {
            *(unsigned*)&dst[(d8 * 8 + 2 * i)     * 72 + vslot] = __builtin_amdgcn_perm(u1[i], u0[i], 0x05040100u);
            *(unsigned*)&dst[(d8 * 8 + 2 * i + 1) * 72 + vslot] = __builtin_amdgcn_perm(u1[i], u0[i], 0x07060302u);
        }
    };

    // Q B-frags: lane (q,t): Q[m = Q0 + w*32 + g*16 + t][k = ks*32 + q*8 ..]
    s16x8 qfrag[2][2];
    #pragma unroll
    for (int g = 0; g < 2; ++g) {
        const unsigned short* qp = Qb + base + (size_t)(Q0 + w * 32 + g * 16 + t) * HD + q * 8;
        qfrag[g][0] = *(const s16x8*)(qp);
        qfrag[g][1] = *(const s16x8*)(qp + 32);
    }

    f32x4 accO[2][4] = {};
    f32x4 accL[2] = {};

    // prologue: stage chunk 0
    issueK(0, Ks[0]);
    {
        uint4 a, bb2; loadV(0, a, bb2); writeV(a, bb2, Vt[0]);
    }
    __syncthreads();

    for (int c = 0; c < n; ++c) {
        const int cur = c & 1;
        const int jbase = c * 64;
        const bool pf = (c + 1 < n);
        uint4 va, vb2;
        if (pf) { issueK(jbase + 64, Ks[cur ^ 1]); loadV(jbase + 64, va, vb2); }

        if (jbase < m_min + 32) {          // wave not fully masked
            const unsigned short* KsB = Ks[cur];
            const unsigned short* VtB = Vt[cur];
            unsigned Pu[2][8];
            #pragma unroll
            for (int g = 0; g < 2; ++g) {
                f32x4 st[4];
                #pragma unroll
                for (int nt = 0; nt < 4; ++nt) {
                    f32x4 zz = {};
                    #pragma unroll
                    for (int ks = 0; ks < 2; ++ks) {
                        s16x8 ak = *(const s16x8*)&KsB[kaddr[nt][ks]];
                        zz = __builtin_amdgcn_mfma_f32_16x16x32_bf16(ak, qfrag[g][ks], zz, 0, 0, 0);
                    }
                    st[nt] = zz;
                }
                if (jbase + 63 > m_min) {  // diagonal-ish chunk: apply causal mask
                    const int ma = m_min + g * 16 + t;
                    #pragma unroll
                    for (int nt = 0; nt < 4; ++nt)
                        #pragma unroll
                        for (int r = 0; r < 4; ++r)
                            if (jbase + nt * 16 + q * 4 + r > ma) st[nt][r] += NEG2;
                }
                #pragma unroll
                for (int nt = 0; nt < 4; ++nt) {
                    float p0 = fexp2(st[nt][0]);
                    float p1 = fexp2(st[nt][1]);
                    float p2 = fexp2(st[nt][2]);
                    float p3 = fexp2(st[nt][3]);
                    Pu[g][2 * nt]     = pk2(p0, p1);
                    Pu[g][2 * nt + 1] = pk2(p2, p3);
                }
            }
            #pragma unroll
            for (int ks = 0; ks < 2; ++ks) {
                #pragma unroll
                for (int nt = 0; nt < 4; ++nt) {
                    s16x8 vb = *(const s16x8*)&VtB[vaddr[nt][ks]];
                    #pragma unroll
                    for (int g = 0; g < 2; ++g)
                        accO[g][nt] = __builtin_amdgcn_mfma_f32_16x16x32_bf16(
                            *(const s16x8*)&Pu[g][ks * 4], vb, accO[g][nt], 0, 0, 0);
                }
                #pragma unroll
                for (int g = 0; g < 2; ++g)
                    accL[g] = __builtin_amdgcn_mfma_f32_16x16x32_bf16(
                        *(const s16x8*)&Pu[g][ks * 4], vone, accL[g], 0, 0, 0);
            }
        }

        if (pf) writeV(va, vb2, Vt[cur ^ 1]);
        __syncthreads();
    }

    // epilogue: out = accO / accL (row layout matches)
    #pragma unroll
    for (int g = 0; g < 2; ++g) {
        f32x4 inv;
        #pragma unroll
        for (int r = 0; r < 4; ++r) inv[r] = 1.0f / accL[g][r];
        #pragma unroll
        for (int nt = 0; nt < 4; ++nt) {
            #pragma unroll
            for (int r = 0; r < 4; ++r) {
                const int row = Q0 + w * 32 + g * 16 + q * 4 + r;
                out[((size_t)(b * L_SEQ + row)) * DMODEL + h * HD + nt * 16 + t] =
                    accO[g][nt][r] * inv[r];
            }
        }
    }
}

// ---------------- launch ----------------
extern "C" void kernel_launch(void* const* d_in, const int* in_sizes, int n_in,
                              void* d_out, int out_size, void* d_ws, size_t ws_size,
                              hipStream_t stream) {
    const float* X  = (const float*)d_in[0];
    const float* Wq = (const float*)d_in[1];
    const float* bq = (const float*)d_in[2];
    const float* Wk = (const float*)d_in[3];
    const float* bk = (const float*)d_in[4];
    const float* Wv = (const float*)d_in[5];
    const float* bv = (const float*)d_in[6];
    float* out = (float*)d_out;

    unsigned short* Xb = (unsigned short*)d_ws;
    unsigned short* Wb = Xb + (size_t)MROWS * DMODEL;
    unsigned short* Yb = Wb + (size_t)3 * DMODEL * DMODEL;

    cvt_all<<<8192 + 3 * 1024, 256, 0, stream>>>(X, Wq, Wk, Wv, Xb, Wb);

    qkv_gemm<<<dim3(64, 8, 3), 256, 0, stream>>>(Xb, Wb, bq, bk, bv, Yb);

    const size_t hs = (size_t)MROWS * DMODEL;
    attn_fwd<<<1024, 256, 0, stream>>>(Yb, Yb + hs, Yb + 2 * hs, out);
}

// Round 8
// 209.602 us; speedup vs baseline: 1.2919x; 1.2919x over previous
//
#include <hip/hip_runtime.h>
#include <hip/hip_bf16.h>

// Problem constants
#define L_SEQ   2048
#define DMODEL  1024
#define NH      16
#define HD      64
#define MROWS   8192          // B*L
// reference: logits = (Q.K) * 1/sqrt(H); fold 0.25*log2(e) into Q -> base-2 softmax
#define QSC     0.360673760222f   // 0.25 * log2(e)
#define NEG2    -2.0e7f           // mask in base-2 domain; exp2 -> exactly 0

typedef float  f32x4 __attribute__((ext_vector_type(4)));
typedef short  s16x8 __attribute__((ext_vector_type(8)));

// round-to-nearest-even f32 -> bf16 bits
__device__ __forceinline__ unsigned short f2bf(float f) {
    union { float f; unsigned u; } v; v.f = f;
    unsigned r = (v.u + 0x7FFFu + ((v.u >> 16) & 1u)) >> 16;
    return (unsigned short)r;
}

__device__ __forceinline__ float fexp2(float x) {
#if __has_builtin(__builtin_amdgcn_exp2f)
    return __builtin_amdgcn_exp2f(x);
#else
    return __expf(x * 0.6931471805599453f);
#endif
}

// pack trunc-bf16(a) low | trunc-bf16(b) high — single v_perm_b32
__device__ __forceinline__ unsigned pk2(float a, float b) {
    union { float f; unsigned u; } ua, ub; ua.f = a; ub.f = b;
    return __builtin_amdgcn_perm(ub.u, ua.u, 0x07060302u);
}

__device__ __forceinline__ void gl_lds16(const void* g, void* l) {
    __builtin_amdgcn_global_load_lds(
        (const __attribute__((address_space(1))) unsigned int*)g,
        (__attribute__((address_space(3))) unsigned int*)l, 16, 0, 0);
}

// ---------------- fused fp32 -> bf16 conversion (X + 3 W's, one dispatch) ----------------
__global__ __launch_bounds__(256) void cvt_all(const float* __restrict__ X,
                                               const float* __restrict__ W0,
                                               const float* __restrict__ W1,
                                               const float* __restrict__ W2,
                                               unsigned short* __restrict__ Xb,
                                               unsigned short* __restrict__ Wb) {
    const int bx = blockIdx.x, tid = threadIdx.x;
    const float* src; unsigned short* dst; int i;
    if (bx < 8192) {                       // X: 8M elems = 2M float4
        src = X; dst = Xb; i = bx * 256 + tid;
    } else {                               // W's: 1M elems = 256K float4 each
        int r = bx - 8192; const int wsel = r >> 10; r &= 1023;
        src = (wsel == 0) ? W0 : (wsel == 1) ? W1 : W2;
        dst = Wb + (size_t)wsel * (DMODEL * DMODEL);
        i = r * 256 + tid;
    }
    float4 v = ((const float4*)src)[i];
    ushort4 o;
    o.x = f2bf(v.x); o.y = f2bf(v.y); o.z = f2bf(v.z); o.w = f2bf(v.w);
    ((ushort4*)dst)[i] = o;
}

// ---------------- QKV projection GEMM: Y = X @ W^T + b ----------------
// BK=64, xor-swizzled LDS, swapped operands, head-major output Y[z][bh][sl][hd].
// Q (z==0) pre-scaled by QSC.
__global__ __launch_bounds__(256, 2) void qkv_gemm(
        const unsigned short* __restrict__ Xb,   // [8192][1024] bf16
        const unsigned short* __restrict__ Wb,   // [3][1024][1024] bf16
        const float* __restrict__ bq, const float* __restrict__ bk_,
        const float* __restrict__ bv,
        unsigned short* __restrict__ Yb) {       // [3][B*H][L][HD] bf16
    __shared__ unsigned short As[128 * 64];
    __shared__ unsigned short Bs[128 * 64];

    const int tid = threadIdx.x;
    const int w = tid >> 6, l = tid & 63, q = l >> 4, t = l & 15;
    const int mw = w >> 1, nw = w & 1;
    const int z = blockIdx.z;
    const int rowM0 = blockIdx.x * 128;
    const int colN0 = blockIdx.y * 128;

    const unsigned short* W = Wb + (size_t)z * (DMODEL * DMODEL);
    unsigned short* Y = Yb + (size_t)z * ((size_t)MROWS * DMODEL);
    const float* bias = (z == 0) ? bq : (z == 1) ? bk_ : bv;
    const float osc = (z == 0) ? QSC : 1.0f;

    f32x4 acc[4][4] = {};   // [in][jm]

    const int srow8 = l >> 3;              // 0..7
    const int sch_g = ((l & 7) ^ srow8) * 8;

    const int coff0 = ((q) ^ (t & 7)) * 8;
    const int coff1 = ((4 + q) ^ (t & 7)) * 8;

    for (int k0 = 0; k0 < DMODEL; k0 += 64) {
        #pragma unroll
        for (int r = 0; r < 4; ++r) {
            const int row = w * 32 + r * 8;
            gl_lds16(Xb + (size_t)(rowM0 + row + srow8) * DMODEL + k0 + sch_g, As + row * 64);
            gl_lds16(W  + (size_t)(colN0 + row + srow8) * DMODEL + k0 + sch_g, Bs + row * 64);
        }
        __syncthreads();
        #pragma unroll
        for (int ks = 0; ks < 2; ++ks) {
            const int co = ks ? coff1 : coff0;
            s16x8 a[4], b[4];
            #pragma unroll
            for (int i = 0; i < 4; ++i) {
                a[i] = *(const s16x8*)&As[(mw * 64 + i * 16 + t) * 64 + co];
                b[i] = *(const s16x8*)&Bs[(nw * 64 + i * 16 + t) * 64 + co];
            }
            #pragma unroll
            for (int in = 0; in < 4; ++in)
                #pragma unroll
                for (int jm = 0; jm < 4; ++jm)
                    acc[in][jm] = __builtin_amdgcn_mfma_f32_16x16x32_bf16(b[in], a[jm], acc[in][jm], 0, 0, 0);
        }
        __syncthreads();
    }

    const int bb = rowM0 >> 11;            // batch
    #pragma unroll
    for (int in = 0; in < 4; ++in) {
        const int ncol = colN0 + nw * 64 + in * 16 + q * 4;
        const int hh = ncol >> 6, hd = ncol & 63;
        const float4 b4 = *(const float4*)&bias[ncol];
        unsigned short* Yh = Y + ((size_t)(bb * NH + hh) * L_SEQ) * HD + hd;
        #pragma unroll
        for (int jm = 0; jm < 4; ++jm) {
            const int sl = (rowM0 & 2047) + mw * 64 + jm * 16 + t;
            unsigned lo = ((unsigned)f2bf((acc[in][jm][0] + b4.x) * osc)) |
                          ((unsigned)f2bf((acc[in][jm][1] + b4.y) * osc) << 16);
            unsigned hi = ((unsigned)f2bf((acc[in][jm][2] + b4.z) * osc)) |
                          ((unsigned)f2bf((acc[in][jm][3] + b4.w) * osc) << 16);
            uint2 o; o.x = lo; o.y = hi;
            *(uint2*)&Yh[(size_t)sl * HD] = o;
        }
    }
}

// ---------------- flash attention fwd (causal), S^T, base-2, NO running max ----------------
// One 128-row q-tile per block; 1024 blocks (4/CU via LDS limit), heavy-first
// (qt descending = LPT greedy), XCD-pinned bh for K/V L2 residency.
// launch_bounds(256,2): NOT 4 — forcing 4 waves/EU caps VGPR at 64 and spills
// the hot loop (R7: +26MB spill WRITE, MfmaUtil halved). LDS already limits
// to 4 blocks/CU; 92 VGPR doesn't.
__global__ __launch_bounds__(256, 2) void attn_fwd(
        const unsigned short* __restrict__ Qb,
        const unsigned short* __restrict__ Kb,
        const unsigned short* __restrict__ Vb,
        float* __restrict__ out) {
    __shared__ __align__(16) unsigned short Ks[2][64 * 64];   // xor-swizzled K tiles
    __shared__ __align__(16) unsigned short Vt[2][64 * 72];   // slot-permuted V^T tiles

    const int tid = threadIdx.x;
    const int w = tid >> 6, l = tid & 63, q = l >> 4, t = l & 15;

    const int lin = blockIdx.x;          // 0..1023
    const int xcd = lin & 7;
    const int bhg = (lin >> 3) & 7;      // 0..7
    const int qt  = 15 - (lin >> 6);     // heavy tiles first
    const int bh  = bhg * 8 + xcd;       // bh & 7 == xcd -> L2-resident K/V per XCD
    const int b = bh >> 4, h = bh & 15;
    const size_t base = (size_t)bh * (L_SEQ * HD);

    const int Q0 = qt * 128;
    const int n = 2 * qt + 2;            // 64-j chunks
    const int m_min = Q0 + w * 32;       // wave's lowest m row

    // V staging: thread covers j-pair {2jp,2jp+1}, d-chunk d8
    const int d8 = tid >> 5, jp = tid & 31;
    const int vslot = ((jp >> 4) << 5) | (((jp >> 1) & 3) << 3) | (((jp >> 3) & 1) << 2) | ((jp & 1) << 1);
    // K async staging (xor-swizzle)
    const int krow_in = l >> 3;
    const int kchunk_g = (l & 7) ^ krow_in;

    int kaddr[4][2], vaddr[4][2];
    #pragma unroll
    for (int nt = 0; nt < 4; ++nt)
        #pragma unroll
        for (int ks = 0; ks < 2; ++ks) {
            kaddr[nt][ks] = (nt * 16 + t) * 64 + (((ks * 4 + q) ^ (t & 7)) * 8);
            vaddr[nt][ks] = (nt * 16 + t) * 72 + ks * 32 + q * 8;
        }

    s16x8 vone;
    #pragma unroll
    for (int i = 0; i < 8; ++i) vone[i] = (short)0x3F80;   // bf16 1.0

    auto issueK = [&](int jbase, unsigned short* dst) {
        #pragma unroll
        for (int r = 0; r < 2; ++r) {
            const int rb = r * 4 + w;
            gl_lds16(Kb + base + (size_t)(jbase + rb * 8 + krow_in) * HD + kchunk_g * 8,
                     dst + rb * 512);
        }
    };
    auto loadV = [&](int jbase, uint4& a, uint4& bb2) {
        const unsigned short* vp = Vb + base + (size_t)(jbase + 2 * jp) * HD + d8 * 8;
        a   = *(const uint4*)vp;
        bb2 = *(const uint4*)(vp + HD);
    };
    auto writeV = [&](const uint4& a, const uint4& bb2, unsigned short* dst) {
        const unsigned* u0 = (const unsigned*)&a;
        const unsigned* u1 = (const unsigned*)&bb2;
        #pragma unroll
        for (int i = 0; i < 4; ++i) {
            *(unsigned*)&dst[(d8 * 8 + 2 * i)     * 72 + vslot] = __builtin_amdgcn_perm(u1[i], u0[i], 0x05040100u);
            *(unsigned*)&dst[(d8 * 8 + 2 * i + 1) * 72 + vslot] = __builtin_amdgcn_perm(u1[i], u0[i], 0x07060302u);
        }
    };

    // Q B-frags: lane (q,t): Q[m = Q0 + w*32 + g*16 + t][k = ks*32 + q*8 ..]
    s16x8 qfrag[2][2];
    #pragma unroll
    for (int g = 0; g < 2; ++g) {
        const unsigned short* qp = Qb + base + (size_t)(Q0 + w * 32 + g * 16 + t) * HD + q * 8;
        qfrag[g][0] = *(const s16x8*)(qp);
        qfrag[g][1] = *(const s16x8*)(qp + 32);
    }

    f32x4 accO[2][4] = {};
    f32x4 accL[2] = {};

    // prologue: stage chunk 0
    issueK(0, Ks[0]);
    {
        uint4 a, bb2; loadV(0, a, bb2); writeV(a, bb2, Vt[0]);
    }
    __syncthreads();

    for (int c = 0; c < n; ++c) {
        const int cur = c & 1;
        const int jbase = c * 64;
        const bool pf = (c + 1 < n);
        uint4 va, vb2;
        if (pf) { issueK(jbase + 64, Ks[cur ^ 1]); loadV(jbase + 64, va, vb2); }

        if (jbase < m_min + 32) {          // wave not fully masked
            const unsigned short* KsB = Ks[cur];
            const unsigned short* VtB = Vt[cur];
            unsigned Pu[2][8];
            #pragma unroll
            for (int g = 0; g < 2; ++g) {
                f32x4 st[4];
                #pragma unroll
                for (int nt = 0; nt < 4; ++nt) {
                    f32x4 zz = {};
                    #pragma unroll
                    for (int ks = 0; ks < 2; ++ks) {
                        s16x8 ak = *(const s16x8*)&KsB[kaddr[nt][ks]];
                        zz = __builtin_amdgcn_mfma_f32_16x16x32_bf16(ak, qfrag[g][ks], zz, 0, 0, 0);
                    }
                    st[nt] = zz;
                }
                if (jbase + 63 > m_min) {  // diagonal-ish chunk: apply causal mask
                    const int ma = m_min + g * 16 + t;
                    #pragma unroll
                    for (int nt = 0; nt < 4; ++nt)
                        #pragma unroll
                        for (int r = 0; r < 4; ++r)
                            if (jbase + nt * 16 + q * 4 + r > ma) st[nt][r] += NEG2;
                }
                #pragma unroll
                for (int nt = 0; nt < 4; ++nt) {
                    float p0 = fexp2(st[nt][0]);
                    float p1 = fexp2(st[nt][1]);
                    float p2 = fexp2(st[nt][2]);
                    float p3 = fexp2(st[nt][3]);
                    Pu[g][2 * nt]     = pk2(p0, p1);
                    Pu[g][2 * nt + 1] = pk2(p2, p3);
                }
            }
            #pragma unroll
            for (int ks = 0; ks < 2; ++ks) {
                #pragma unroll
                for (int nt = 0; nt < 4; ++nt) {
                    s16x8 vb = *(const s16x8*)&VtB[vaddr[nt][ks]];
                    #pragma unroll
                    for (int g = 0; g < 2; ++g)
                        accO[g][nt] = __builtin_amdgcn_mfma_f32_16x16x32_bf16(
                            *(const s16x8*)&Pu[g][ks * 4], vb, accO[g][nt], 0, 0, 0);
                }
                #pragma unroll
                for (int g = 0; g < 2; ++g)
                    accL[g] = __builtin_amdgcn_mfma_f32_16x16x32_bf16(
                        *(const s16x8*)&Pu[g][ks * 4], vone, accL[g], 0, 0, 0);
            }
        }

        if (pf) writeV(va, vb2, Vt[cur ^ 1]);
        __syncthreads();
    }

    // epilogue: out = accO / accL (row layout matches)
    #pragma unroll
    for (int g = 0; g < 2; ++g) {
        f32x4 inv;
        #pragma unroll
        for (int r = 0; r < 4; ++r) inv[r] = 1.0f / accL[g][r];
        #pragma unroll
        for (int nt = 0; nt < 4; ++nt) {
            #pragma unroll
            for (int r = 0; r < 4; ++r) {
                const int row = Q0 + w * 32 + g * 16 + q * 4 + r;
                out[((size_t)(b * L_SEQ + row)) * DMODEL + h * HD + nt * 16 + t] =
                    accO[g][nt][r] * inv[r];
            }
        }
    }
}

// ---------------- launch ----------------
extern "C" void kernel_launch(void* const* d_in, const int* in_sizes, int n_in,
                              void* d_out, int out_size, void* d_ws, size_t ws_size,
                              hipStream_t stream) {
    const float* X  = (const float*)d_in[0];
    const float* Wq = (const float*)d_in[1];
    const float* bq = (const float*)d_in[2];
    const float* Wk = (const float*)d_in[3];
    const float* bk = (const float*)d_in[4];
    const float* Wv = (const float*)d_in[5];
    const float* bv = (const float*)d_in[6];
    float* out = (float*)d_out;

    unsigned short* Xb = (unsigned short*)d_ws;
    unsigned short* Wb = Xb + (size_t)MROWS * DMODEL;
    unsigned short* Yb = Wb + (size_t)3 * DMODEL * DMODEL;

    cvt_all<<<8192 + 3 * 1024, 256, 0, stream>>>(X, Wq, Wk, Wv, Xb, Wb);

    qkv_gemm<<<dim3(64, 8, 3), 256, 0, stream>>>(Xb, Wb, bq, bk, bv, Yb);

    const size_t hs = (size_t)MROWS * DMODEL;
    attn_fwd<<<1024, 256, 0, stream>>>(Yb, Yb + hs, Yb + 2 * hs, out);
}

// Round 9
// 192.017 us; speedup vs baseline: 1.4102x; 1.0916x over previous
//
#include <hip/hip_runtime.h>
#include <hip/hip_bf16.h>

// Problem constants
#define L_SEQ   2048
#define DMODEL  1024
#define NH      16
#define HD      64
#define MROWS   8192          // B*L
// reference: logits = (Q.K) * 1/sqrt(H); fold 0.25*log2(e) into Q -> base-2 softmax
#define QSC     0.360673760222f   // 0.25 * log2(e)
#define NEG2    -2.0e7f           // mask in base-2 domain; exp2 -> exactly 0

typedef float  f32x4 __attribute__((ext_vector_type(4)));
typedef short  s16x8 __attribute__((ext_vector_type(8)));

// round-to-nearest-even f32 -> bf16 bits
__device__ __forceinline__ unsigned short f2bf(float f) {
    union { float f; unsigned u; } v; v.f = f;
    unsigned r = (v.u + 0x7FFFu + ((v.u >> 16) & 1u)) >> 16;
    return (unsigned short)r;
}

__device__ __forceinline__ float fexp2(float x) {
#if __has_builtin(__builtin_amdgcn_exp2f)
    return __builtin_amdgcn_exp2f(x);
#else
    return __expf(x * 0.6931471805599453f);
#endif
}

// pack trunc-bf16(a) low | trunc-bf16(b) high — single v_perm_b32
__device__ __forceinline__ unsigned pk2(float a, float b) {
    union { float f; unsigned u; } ua, ub; ua.f = a; ub.f = b;
    return __builtin_amdgcn_perm(ub.u, ua.u, 0x07060302u);
}

__device__ __forceinline__ void gl_lds16(const void* g, void* l) {
    __builtin_amdgcn_global_load_lds(
        (const __attribute__((address_space(1))) unsigned int*)g,
        (__attribute__((address_space(3))) unsigned int*)l, 16, 0, 0);
}

// ---------------- fused fp32 -> bf16 conversion (X + 3 W's, one dispatch) ----------------
__global__ __launch_bounds__(256) void cvt_all(const float* __restrict__ X,
                                               const float* __restrict__ W0,
                                               const float* __restrict__ W1,
                                               const float* __restrict__ W2,
                                               unsigned short* __restrict__ Xb,
                                               unsigned short* __restrict__ Wb) {
    const int bx = blockIdx.x, tid = threadIdx.x;
    const float* src; unsigned short* dst; int i;
    if (bx < 8192) {                       // X: 8M elems = 2M float4
        src = X; dst = Xb; i = bx * 256 + tid;
    } else {                               // W's: 1M elems = 256K float4 each
        int r = bx - 8192; const int wsel = r >> 10; r &= 1023;
        src = (wsel == 0) ? W0 : (wsel == 1) ? W1 : W2;
        dst = Wb + (size_t)wsel * (DMODEL * DMODEL);
        i = r * 256 + tid;
    }
    float4 v = ((const float4*)src)[i];
    ushort4 o;
    o.x = f2bf(v.x); o.y = f2bf(v.y); o.z = f2bf(v.z); o.w = f2bf(v.w);
    ((ushort4*)dst)[i] = o;
}

// ---------------- QKV projection GEMM: Y = X @ W^T + b ----------------
// BK=64, xor-swizzled LDS, swapped operands.
// Q/K (z==0/1): head-major rows Y[z][bh][sl][hd]; Q pre-scaled by QSC.
// V  (z==2):   TRANSPOSED per head: VT[bh][d][sl'] with the attn P-fragment
//              slot permutation applied within each 64-slot group, so attn can
//              stage V exactly like K (async DMA + xor swizzle, no in-kernel
//              transpose).
__global__ __launch_bounds__(256, 2) void qkv_gemm(
        const unsigned short* __restrict__ Xb,   // [8192][1024] bf16
        const unsigned short* __restrict__ Wb,   // [3][1024][1024] bf16
        const float* __restrict__ bq, const float* __restrict__ bk_,
        const float* __restrict__ bv,
        unsigned short* __restrict__ Yb) {
    __shared__ unsigned short As[128 * 64];
    __shared__ unsigned short Bs[128 * 64];

    const int tid = threadIdx.x;
    const int w = tid >> 6, l = tid & 63, q = l >> 4, t = l & 15;
    const int mw = w >> 1, nw = w & 1;
    const int z = blockIdx.z;
    const int rowM0 = blockIdx.x * 128;
    const int colN0 = blockIdx.y * 128;

    const unsigned short* W = Wb + (size_t)z * (DMODEL * DMODEL);
    unsigned short* Y = Yb + (size_t)z * ((size_t)MROWS * DMODEL);
    const float* bias = (z == 0) ? bq : (z == 1) ? bk_ : bv;
    const float osc = (z == 0) ? QSC : 1.0f;

    f32x4 acc[4][4] = {};   // [in][jm]

    const int srow8 = l >> 3;              // 0..7
    const int sch_g = ((l & 7) ^ srow8) * 8;

    const int coff0 = ((q) ^ (t & 7)) * 8;
    const int coff1 = ((4 + q) ^ (t & 7)) * 8;

    for (int k0 = 0; k0 < DMODEL; k0 += 64) {
        #pragma unroll
        for (int r = 0; r < 4; ++r) {
            const int row = w * 32 + r * 8;
            gl_lds16(Xb + (size_t)(rowM0 + row + srow8) * DMODEL + k0 + sch_g, As + row * 64);
            gl_lds16(W  + (size_t)(colN0 + row + srow8) * DMODEL + k0 + sch_g, Bs + row * 64);
        }
        __syncthreads();
        #pragma unroll
        for (int ks = 0; ks < 2; ++ks) {
            const int co = ks ? coff1 : coff0;
            s16x8 a[4], b[4];
            #pragma unroll
            for (int i = 0; i < 4; ++i) {
                a[i] = *(const s16x8*)&As[(mw * 64 + i * 16 + t) * 64 + co];
                b[i] = *(const s16x8*)&Bs[(nw * 64 + i * 16 + t) * 64 + co];
            }
            #pragma unroll
            for (int in = 0; in < 4; ++in)
                #pragma unroll
                for (int jm = 0; jm < 4; ++jm)
                    acc[in][jm] = __builtin_amdgcn_mfma_f32_16x16x32_bf16(b[in], a[jm], acc[in][jm], 0, 0, 0);
        }
        __syncthreads();
    }

    const int bb = rowM0 >> 11;            // batch
    if (z < 2) {
        // row-major head-major store; lane holds 4 consecutive hd -> uint2
        #pragma unroll
        for (int in = 0; in < 4; ++in) {
            const int ncol = colN0 + nw * 64 + in * 16 + q * 4;
            const int hh = ncol >> 6, hd = ncol & 63;
            const float4 b4 = *(const float4*)&bias[ncol];
            unsigned short* Yh = Y + ((size_t)(bb * NH + hh) * L_SEQ) * HD + hd;
            #pragma unroll
            for (int jm = 0; jm < 4; ++jm) {
                const int sl = (rowM0 & 2047) + mw * 64 + jm * 16 + t;
                unsigned lo = ((unsigned)f2bf((acc[in][jm][0] + b4.x) * osc)) |
                              ((unsigned)f2bf((acc[in][jm][1] + b4.y) * osc) << 16);
                unsigned hi = ((unsigned)f2bf((acc[in][jm][2] + b4.z) * osc)) |
                              ((unsigned)f2bf((acc[in][jm][3] + b4.w) * osc) << 16);
                uint2 o; o.x = lo; o.y = hi;
                *(uint2*)&Yh[(size_t)sl * HD] = o;
            }
        }
    } else {
        // V^T store: VT[bh][d][sl'], sl' = g64 + perm(j) where j = jm*16+t,
        // perm(j) = (jm>>1)*32 + (t>>2)*8 + (jm&1)*4 + (t&3)  [attn P-slot order]
        const int g64 = (rowM0 & 2047) + mw * 64;
        #pragma unroll
        for (int in = 0; in < 4; ++in) {
            const int ncol = colN0 + nw * 64 + in * 16 + q * 4;
            const int hh = ncol >> 6;
            const int d0 = in * 16 + q * 4;
            const float4 b4 = *(const float4*)&bias[ncol];
            unsigned short* Yh = Y + (size_t)(bb * NH + hh) * (L_SEQ * HD);
            #pragma unroll
            for (int jm = 0; jm < 4; ++jm) {
                const int slot = g64 + ((jm >> 1) << 5) + ((t >> 2) << 3) + ((jm & 1) << 2) + (t & 3);
                Yh[(size_t)(d0 + 0) * L_SEQ + slot] = f2bf(acc[in][jm][0] + b4.x);
                Yh[(size_t)(d0 + 1) * L_SEQ + slot] = f2bf(acc[in][jm][1] + b4.y);
                Yh[(size_t)(d0 + 2) * L_SEQ + slot] = f2bf(acc[in][jm][2] + b4.z);
                Yh[(size_t)(d0 + 3) * L_SEQ + slot] = f2bf(acc[in][jm][3] + b4.w);
            }
        }
    }
}

// ---------------- flash attention fwd (causal), S^T, base-2, NO running max ----------------
// One 128-row q-tile per block; 1024 blocks, heavy-first (LPT), XCD-pinned bh.
// K AND V both staged via async gl_lds16 (V pre-transposed+slot-permuted by gemm).
// LDS 32 KB -> up to 5 blocks/CU. launch_bounds(256,2): (256,4) spills (R7).
__global__ __launch_bounds__(256, 2) void attn_fwd(
        const unsigned short* __restrict__ Qb,
        const unsigned short* __restrict__ Kb,
        const unsigned short* __restrict__ VTb,   // [bh][d][sl'] bf16
        float* __restrict__ out) {
    __shared__ __align__(16) unsigned short Ks[2][64 * 64];   // xor-swizzled K tiles
    __shared__ __align__(16) unsigned short Vt[2][64 * 64];   // xor-swizzled V^T tiles

    const int tid = threadIdx.x;
    const int w = tid >> 6, l = tid & 63, q = l >> 4, t = l & 15;

    const int lin = blockIdx.x;          // 0..1023
    const int xcd = lin & 7;
    const int bhg = (lin >> 3) & 7;      // 0..7
    const int qt  = 15 - (lin >> 6);     // heavy tiles first
    const int bh  = bhg * 8 + xcd;       // bh & 7 == xcd -> L2-resident K/V per XCD
    const int b = bh >> 4, h = bh & 15;
    const size_t base = (size_t)bh * (L_SEQ * HD);

    const int Q0 = qt * 128;
    const int n = 2 * qt + 2;            // 64-j chunks
    const int m_min = Q0 + w * 32;       // wave's lowest m row

    // async staging (xor-swizzle), identical for K and V^T
    const int krow_in = l >> 3;
    const int kchunk_g = (l & 7) ^ krow_in;

    int kaddr[4][2];
    #pragma unroll
    for (int nt = 0; nt < 4; ++nt)
        #pragma unroll
        for (int ks = 0; ks < 2; ++ks)
            kaddr[nt][ks] = (nt * 16 + t) * 64 + (((ks * 4 + q) ^ (t & 7)) * 8);

    s16x8 vone;
    #pragma unroll
    for (int i = 0; i < 8; ++i) vone[i] = (short)0x3F80;   // bf16 1.0

    auto issueK = [&](int jbase, unsigned short* dst) {
        #pragma unroll
        for (int r = 0; r < 2; ++r) {
            const int rb = r * 4 + w;
            gl_lds16(Kb + base + (size_t)(jbase + rb * 8 + krow_in) * HD + kchunk_g * 8,
                     dst + rb * 512);
        }
    };
    auto issueV = [&](int jbase, unsigned short* dst) {
        #pragma unroll
        for (int r = 0; r < 2; ++r) {
            const int rb = r * 4 + w;   // d-row = rb*8 + krow_in
            gl_lds16(VTb + base + (size_t)(rb * 8 + krow_in) * L_SEQ + jbase + kchunk_g * 8,
                     dst + rb * 512);
        }
    };

    // Q B-frags: lane (q,t): Q[m = Q0 + w*32 + g*16 + t][k = ks*32 + q*8 ..]
    s16x8 qfrag[2][2];
    #pragma unroll
    for (int g = 0; g < 2; ++g) {
        const unsigned short* qp = Qb + base + (size_t)(Q0 + w * 32 + g * 16 + t) * HD + q * 8;
        qfrag[g][0] = *(const s16x8*)(qp);
        qfrag[g][1] = *(const s16x8*)(qp + 32);
    }

    f32x4 accO[2][4] = {};
    f32x4 accL[2] = {};

    // prologue: stage chunk 0
    issueK(0, Ks[0]);
    issueV(0, Vt[0]);
    __syncthreads();

    for (int c = 0; c < n; ++c) {
        const int cur = c & 1;
        const int jbase = c * 64;
        if (c + 1 < n) { issueK(jbase + 64, Ks[cur ^ 1]); issueV(jbase + 64, Vt[cur ^ 1]); }

        if (jbase < m_min + 32) {          // wave not fully masked
            const unsigned short* KsB = Ks[cur];
            const unsigned short* VtB = Vt[cur];
            unsigned Pu[2][8];
            #pragma unroll
            for (int g = 0; g < 2; ++g) {
                f32x4 st[4];
                #pragma unroll
                for (int nt = 0; nt < 4; ++nt) {
                    f32x4 zz = {};
                    #pragma unroll
                    for (int ks = 0; ks < 2; ++ks) {
                        s16x8 ak = *(const s16x8*)&KsB[kaddr[nt][ks]];
                        zz = __builtin_amdgcn_mfma_f32_16x16x32_bf16(ak, qfrag[g][ks], zz, 0, 0, 0);
                    }
                    st[nt] = zz;
                }
                if (jbase + 63 > m_min) {  // diagonal-ish chunk: apply causal mask
                    const int ma = m_min + g * 16 + t;
                    #pragma unroll
                    for (int nt = 0; nt < 4; ++nt)
                        #pragma unroll
                        for (int r = 0; r < 4; ++r)
                            if (jbase + nt * 16 + q * 4 + r > ma) st[nt][r] += NEG2;
                }
                #pragma unroll
                for (int nt = 0; nt < 4; ++nt) {
                    float p0 = fexp2(st[nt][0]);
                    float p1 = fexp2(st[nt][1]);
                    float p2 = fexp2(st[nt][2]);
                    float p3 = fexp2(st[nt][3]);
                    Pu[g][2 * nt]     = pk2(p0, p1);
                    Pu[g][2 * nt + 1] = pk2(p2, p3);
                }
            }
            #pragma unroll
            for (int ks = 0; ks < 2; ++ks) {
                #pragma unroll
                for (int nt = 0; nt < 4; ++nt) {
                    s16x8 vb = *(const s16x8*)&VtB[kaddr[nt][ks]];
                    #pragma unroll
                    for (int g = 0; g < 2; ++g)
                        accO[g][nt] = __builtin_amdgcn_mfma_f32_16x16x32_bf16(
                            *(const s16x8*)&Pu[g][ks * 4], vb, accO[g][nt], 0, 0, 0);
                }
                #pragma unroll
                for (int g = 0; g < 2; ++g)
                    accL[g] = __builtin_amdgcn_mfma_f32_16x16x32_bf16(
                        *(const s16x8*)&Pu[g][ks * 4], vone, accL[g], 0, 0, 0);
            }
        }

        __syncthreads();
    }

    // epilogue: out = accO / accL (row layout matches)
    #pragma unroll
    for (int g = 0; g < 2; ++g) {
        f32x4 inv;
        #pragma unroll
        for (int r = 0; r < 4; ++r) inv[r] = 1.0f / accL[g][r];
        #pragma unroll
        for (int nt = 0; nt < 4; ++nt) {
            #pragma unroll
            for (int r = 0; r < 4; ++r) {
                const int row = Q0 + w * 32 + g * 16 + q * 4 + r;
                out[((size_t)(b * L_SEQ + row)) * DMODEL + h * HD + nt * 16 + t] =
                    accO[g][nt][r] * inv[r];
            }
        }
    }
}

// ---------------- launch ----------------
extern "C" void kernel_launch(void* const* d_in, const int* in_sizes, int n_in,
                              void* d_out, int out_size, void* d_ws, size_t ws_size,
                              hipStream_t stream) {
    const float* X  = (const float*)d_in[0];
    const float* Wq = (const float*)d_in[1];
    const float* bq = (const float*)d_in[2];
    const float* Wk = (const float*)d_in[3];
    const float* bk = (const float*)d_in[4];
    const float* Wv = (const float*)d_in[5];
    const float* bv = (const float*)d_in[6];
    float* out = (float*)d_out;

    unsigned short* Xb = (unsigned short*)d_ws;
    unsigned short* Wb = Xb + (size_t)MROWS * DMODEL;
    unsigned short* Yb = Wb + (size_t)3 * DMODEL * DMODEL;

    cvt_all<<<8192 + 3 * 1024, 256, 0, stream>>>(X, Wq, Wk, Wv, Xb, Wb);

    qkv_gemm<<<dim3(64, 8, 3), 256, 0, stream>>>(Xb, Wb, bq, bk, bv, Yb);

    const size_t hs = (size_t)MROWS * DMODEL;
    attn_fwd<<<1024, 256, 0, stream>>>(Yb, Yb + hs, Yb + 2 * hs, out);
}

// Round 10
// 189.516 us; speedup vs baseline: 1.4288x; 1.0132x over previous
//
#include <hip/hip_runtime.h>
#include <hip/hip_bf16.h>

// Problem constants
#define L_SEQ   2048
#define DMODEL  1024
#define NH      16
#define HD      64
#define MROWS   8192          // B*L
// reference: logits = (Q.K) * 1/sqrt(H); fold 0.25*log2(e) into Q -> base-2 softmax
#define QSC     0.360673760222f   // 0.25 * log2(e)
#define NEG2    -2.0e7f           // mask in base-2 domain; exp2 -> exactly 0

typedef float  f32x4 __attribute__((ext_vector_type(4)));
typedef short  s16x8 __attribute__((ext_vector_type(8)));

// round-to-nearest-even f32 -> bf16 bits
__device__ __forceinline__ unsigned short f2bf(float f) {
    union { float f; unsigned u; } v; v.f = f;
    unsigned r = (v.u + 0x7FFFu + ((v.u >> 16) & 1u)) >> 16;
    return (unsigned short)r;
}

__device__ __forceinline__ float fexp2(float x) {
#if __has_builtin(__builtin_amdgcn_exp2f)
    return __builtin_amdgcn_exp2f(x);
#else
    return __expf(x * 0.6931471805599453f);
#endif
}

// pack trunc-bf16(a) low | trunc-bf16(b) high — single v_perm_b32
__device__ __forceinline__ unsigned pk2(float a, float b) {
    union { float f; unsigned u; } ua, ub; ua.f = a; ub.f = b;
    return __builtin_amdgcn_perm(ub.u, ua.u, 0x07060302u);
}

__device__ __forceinline__ void gl_lds16(const void* g, void* l) {
    __builtin_amdgcn_global_load_lds(
        (const __attribute__((address_space(1))) unsigned int*)g,
        (__attribute__((address_space(3))) unsigned int*)l, 16, 0, 0);
}

// ---------------- fused fp32 -> bf16 conversion, 4x grid-stride ----------------
// X: 2M float4 -> 2048 blocks x 4 iters; each W: 256K float4 -> 256 blocks x 4.
__global__ __launch_bounds__(256) void cvt_all(const float* __restrict__ X,
                                               const float* __restrict__ W0,
                                               const float* __restrict__ W1,
                                               const float* __restrict__ W2,
                                               unsigned short* __restrict__ Xb,
                                               unsigned short* __restrict__ Wb) {
    const int bx = blockIdx.x, tid = threadIdx.x;
    const float* src; unsigned short* dst; int i0;
    if (bx < 2048) {
        src = X; dst = Xb; i0 = bx * 1024 + tid;
    } else {
        int r = bx - 2048; const int wsel = r >> 8; r &= 255;
        src = (wsel == 0) ? W0 : (wsel == 1) ? W1 : W2;
        dst = Wb + (size_t)wsel * (DMODEL * DMODEL);
        i0 = r * 1024 + tid;
    }
    #pragma unroll
    for (int k = 0; k < 4; ++k) {
        const int i = i0 + k * 256;
        float4 v = ((const float4*)src)[i];
        ushort4 o;
        o.x = f2bf(v.x); o.y = f2bf(v.y); o.z = f2bf(v.z); o.w = f2bf(v.w);
        ((ushort4*)dst)[i] = o;
    }
}

// ---------------- QKV projection GEMM: Y = X @ W^T + b ----------------
// BK=64, xor-swizzled LDS, swapped operands.
// Q/K (z==0/1): head-major rows Y[z][bh][sl][hd]; Q pre-scaled by QSC.
// V  (z==2):   transposed per head VT[bh][d][sl'] with attn P-slot permutation.
__global__ __launch_bounds__(256, 2) void qkv_gemm(
        const unsigned short* __restrict__ Xb,   // [8192][1024] bf16
        const unsigned short* __restrict__ Wb,   // [3][1024][1024] bf16
        const float* __restrict__ bq, const float* __restrict__ bk_,
        const float* __restrict__ bv,
        unsigned short* __restrict__ Yb) {
    __shared__ unsigned short As[128 * 64];
    __shared__ unsigned short Bs[128 * 64];

    const int tid = threadIdx.x;
    const int w = tid >> 6, l = tid & 63, q = l >> 4, t = l & 15;
    const int mw = w >> 1, nw = w & 1;
    const int z = blockIdx.z;
    const int rowM0 = blockIdx.x * 128;
    const int colN0 = blockIdx.y * 128;

    const unsigned short* W = Wb + (size_t)z * (DMODEL * DMODEL);
    unsigned short* Y = Yb + (size_t)z * ((size_t)MROWS * DMODEL);
    const float* bias = (z == 0) ? bq : (z == 1) ? bk_ : bv;
    const float osc = (z == 0) ? QSC : 1.0f;

    f32x4 acc[4][4] = {};   // [in][jm]

    const int srow8 = l >> 3;              // 0..7
    const int sch_g = ((l & 7) ^ srow8) * 8;

    const int coff0 = ((q) ^ (t & 7)) * 8;
    const int coff1 = ((4 + q) ^ (t & 7)) * 8;

    for (int k0 = 0; k0 < DMODEL; k0 += 64) {
        #pragma unroll
        for (int r = 0; r < 4; ++r) {
            const int row = w * 32 + r * 8;
            gl_lds16(Xb + (size_t)(rowM0 + row + srow8) * DMODEL + k0 + sch_g, As + row * 64);
            gl_lds16(W  + (size_t)(colN0 + row + srow8) * DMODEL + k0 + sch_g, Bs + row * 64);
        }
        __syncthreads();
        #pragma unroll
        for (int ks = 0; ks < 2; ++ks) {
            const int co = ks ? coff1 : coff0;
            s16x8 a[4], b[4];
            #pragma unroll
            for (int i = 0; i < 4; ++i) {
                a[i] = *(const s16x8*)&As[(mw * 64 + i * 16 + t) * 64 + co];
                b[i] = *(const s16x8*)&Bs[(nw * 64 + i * 16 + t) * 64 + co];
            }
            #pragma unroll
            for (int in = 0; in < 4; ++in)
                #pragma unroll
                for (int jm = 0; jm < 4; ++jm)
                    acc[in][jm] = __builtin_amdgcn_mfma_f32_16x16x32_bf16(b[in], a[jm], acc[in][jm], 0, 0, 0);
        }
        __syncthreads();
    }

    const int bb = rowM0 >> 11;            // batch
    if (z < 2) {
        #pragma unroll
        for (int in = 0; in < 4; ++in) {
            const int ncol = colN0 + nw * 64 + in * 16 + q * 4;
            const int hh = ncol >> 6, hd = ncol & 63;
            const float4 b4 = *(const float4*)&bias[ncol];
            unsigned short* Yh = Y + ((size_t)(bb * NH + hh) * L_SEQ) * HD + hd;
            #pragma unroll
            for (int jm = 0; jm < 4; ++jm) {
                const int sl = (rowM0 & 2047) + mw * 64 + jm * 16 + t;
                unsigned lo = ((unsigned)f2bf((acc[in][jm][0] + b4.x) * osc)) |
                              ((unsigned)f2bf((acc[in][jm][1] + b4.y) * osc) << 16);
                unsigned hi = ((unsigned)f2bf((acc[in][jm][2] + b4.z) * osc)) |
                              ((unsigned)f2bf((acc[in][jm][3] + b4.w) * osc) << 16);
                uint2 o; o.x = lo; o.y = hi;
                *(uint2*)&Yh[(size_t)sl * HD] = o;
            }
        }
    } else {
        // V^T store: VT[bh][d][sl'], sl' = g64 + perm(j), j = jm*16+t,
        // perm(j) = (jm>>1)*32 + (t>>2)*8 + (jm&1)*4 + (t&3)
        const int g64 = (rowM0 & 2047) + mw * 64;
        #pragma unroll
        for (int in = 0; in < 4; ++in) {
            const int ncol = colN0 + nw * 64 + in * 16 + q * 4;
            const int hh = ncol >> 6;
            const int d0 = in * 16 + q * 4;
            const float4 b4 = *(const float4*)&bias[ncol];
            unsigned short* Yh = Y + (size_t)(bb * NH + hh) * (L_SEQ * HD);
            #pragma unroll
            for (int jm = 0; jm < 4; ++jm) {
                const int slot = g64 + ((jm >> 1) << 5) + ((t >> 2) << 3) + ((jm & 1) << 2) + (t & 3);
                Yh[(size_t)(d0 + 0) * L_SEQ + slot] = f2bf(acc[in][jm][0] + b4.x);
                Yh[(size_t)(d0 + 1) * L_SEQ + slot] = f2bf(acc[in][jm][1] + b4.y);
                Yh[(size_t)(d0 + 2) * L_SEQ + slot] = f2bf(acc[in][jm][2] + b4.z);
                Yh[(size_t)(d0 + 3) * L_SEQ + slot] = f2bf(acc[in][jm][3] + b4.w);
            }
        }
    }
}

// ---------------- flash attention fwd (causal), S^T, base-2, NO running max ----------------
// One 128-row q-tile per block; 1024 blocks, heavy-first (LPT), XCD-pinned bh.
// K AND V staged via async gl_lds16 (V pre-transposed+slot-permuted by gemm).
// K-fragments hoisted into registers once per chunk, shared by both m-groups.
// launch_bounds(256,2): (256,4) caps VGPR at 64 and spills (R7).
__global__ __launch_bounds__(256, 2) void attn_fwd(
        const unsigned short* __restrict__ Qb,
        const unsigned short* __restrict__ Kb,
        const unsigned short* __restrict__ VTb,   // [bh][d][sl'] bf16
        float* __restrict__ out) {
    __shared__ __align__(16) unsigned short Ks[2][64 * 64];   // xor-swizzled K tiles
    __shared__ __align__(16) unsigned short Vt[2][64 * 64];   // xor-swizzled V^T tiles

    const int tid = threadIdx.x;
    const int w = tid >> 6, l = tid & 63, q = l >> 4, t = l & 15;

    const int lin = blockIdx.x;          // 0..1023
    const int xcd = lin & 7;
    const int bhg = (lin >> 3) & 7;      // 0..7
    const int qt  = 15 - (lin >> 6);     // heavy tiles first
    const int bh  = bhg * 8 + xcd;       // bh & 7 == xcd -> L2-resident K/V per XCD
    const int b = bh >> 4, h = bh & 15;
    const size_t base = (size_t)bh * (L_SEQ * HD);

    const int Q0 = qt * 128;
    const int n = 2 * qt + 2;            // 64-j chunks
    const int m_min = Q0 + w * 32;       // wave's lowest m row

    // async staging (xor-swizzle), identical for K and V^T
    const int krow_in = l >> 3;
    const int kchunk_g = (l & 7) ^ krow_in;

    int kaddr[4][2];
    #pragma unroll
    for (int nt = 0; nt < 4; ++nt)
        #pragma unroll
        for (int ks = 0; ks < 2; ++ks)
            kaddr[nt][ks] = (nt * 16 + t) * 64 + (((ks * 4 + q) ^ (t & 7)) * 8);

    s16x8 vone;
    #pragma unroll
    for (int i = 0; i < 8; ++i) vone[i] = (short)0x3F80;   // bf16 1.0

    auto issueK = [&](int jbase, unsigned short* dst) {
        #pragma unroll
        for (int r = 0; r < 2; ++r) {
            const int rb = r * 4 + w;
            gl_lds16(Kb + base + (size_t)(jbase + rb * 8 + krow_in) * HD + kchunk_g * 8,
                     dst + rb * 512);
        }
    };
    auto issueV = [&](int jbase, unsigned short* dst) {
        #pragma unroll
        for (int r = 0; r < 2; ++r) {
            const int rb = r * 4 + w;   // d-row = rb*8 + krow_in
            gl_lds16(VTb + base + (size_t)(rb * 8 + krow_in) * L_SEQ + jbase + kchunk_g * 8,
                     dst + rb * 512);
        }
    };

    // Q B-frags: lane (q,t): Q[m = Q0 + w*32 + g*16 + t][k = ks*32 + q*8 ..]
    s16x8 qfrag[2][2];
    #pragma unroll
    for (int g = 0; g < 2; ++g) {
        const unsigned short* qp = Qb + base + (size_t)(Q0 + w * 32 + g * 16 + t) * HD + q * 8;
        qfrag[g][0] = *(const s16x8*)(qp);
        qfrag[g][1] = *(const s16x8*)(qp + 32);
    }

    f32x4 accO[2][4] = {};
    f32x4 accL[2] = {};

    // prologue: stage chunk 0
    issueK(0, Ks[0]);
    issueV(0, Vt[0]);
    __syncthreads();

    for (int c = 0; c < n; ++c) {
        const int cur = c & 1;
        const int jbase = c * 64;
        if (c + 1 < n) { issueK(jbase + 64, Ks[cur ^ 1]); issueV(jbase + 64, Vt[cur ^ 1]); }

        if (jbase < m_min + 32) {          // wave not fully masked
            const unsigned short* KsB = Ks[cur];
            const unsigned short* VtB = Vt[cur];

            // hoist K-frags once; reuse for both m-groups
            s16x8 akf[4][2];
            #pragma unroll
            for (int nt = 0; nt < 4; ++nt)
                #pragma unroll
                for (int ks = 0; ks < 2; ++ks)
                    akf[nt][ks] = *(const s16x8*)&KsB[kaddr[nt][ks]];

            unsigned Pu[2][8];
            #pragma unroll
            for (int g = 0; g < 2; ++g) {
                f32x4 st[4];
                #pragma unroll
                for (int nt = 0; nt < 4; ++nt) {
                    f32x4 zz = {};
                    #pragma unroll
                    for (int ks = 0; ks < 2; ++ks)
                        zz = __builtin_amdgcn_mfma_f32_16x16x32_bf16(akf[nt][ks], qfrag[g][ks], zz, 0, 0, 0);
                    st[nt] = zz;
                }
                if (jbase + 63 > m_min) {  // diagonal-ish chunk: apply causal mask
                    const int ma = m_min + g * 16 + t;
                    #pragma unroll
                    for (int nt = 0; nt < 4; ++nt)
                        #pragma unroll
                        for (int r = 0; r < 4; ++r)
                            if (jbase + nt * 16 + q * 4 + r > ma) st[nt][r] += NEG2;
                }
                #pragma unroll
                for (int nt = 0; nt < 4; ++nt) {
                    float p0 = fexp2(st[nt][0]);
                    float p1 = fexp2(st[nt][1]);
                    float p2 = fexp2(st[nt][2]);
                    float p3 = fexp2(st[nt][3]);
                    Pu[g][2 * nt]     = pk2(p0, p1);
                    Pu[g][2 * nt + 1] = pk2(p2, p3);
                }
            }
            #pragma unroll
            for (int ks = 0; ks < 2; ++ks) {
                #pragma unroll
                for (int nt = 0; nt < 4; ++nt) {
                    s16x8 vb = *(const s16x8*)&VtB[kaddr[nt][ks]];
                    #pragma unroll
                    for (int g = 0; g < 2; ++g)
                        accO[g][nt] = __builtin_amdgcn_mfma_f32_16x16x32_bf16(
                            *(const s16x8*)&Pu[g][ks * 4], vb, accO[g][nt], 0, 0, 0);
                }
                #pragma unroll
                for (int g = 0; g < 2; ++g)
                    accL[g] = __builtin_amdgcn_mfma_f32_16x16x32_bf16(
                        *(const s16x8*)&Pu[g][ks * 4], vone, accL[g], 0, 0, 0);
            }
        }

        __syncthreads();
    }

    // epilogue: out = accO / accL (row layout matches)
    #pragma unroll
    for (int g = 0; g < 2; ++g) {
        f32x4 inv;
        #pragma unroll
        for (int r = 0; r < 4; ++r) inv[r] = 1.0f / accL[g][r];
        #pragma unroll
        for (int nt = 0; nt < 4; ++nt) {
            #pragma unroll
            for (int r = 0; r < 4; ++r) {
                const int row = Q0 + w * 32 + g * 16 + q * 4 + r;
                out[((size_t)(b * L_SEQ + row)) * DMODEL + h * HD + nt * 16 + t] =
                    accO[g][nt][r] * inv[r];
            }
        }
    }
}

// ---------------- launch ----------------
extern "C" void kernel_launch(void* const* d_in, const int* in_sizes, int n_in,
                              void* d_out, int out_size, void* d_ws, size_t ws_size,
                              hipStream_t stream) {
    const float* X  = (const float*)d_in[0];
    const float* Wq = (const float*)d_in[1];
    const float* bq = (const float*)d_in[2];
    const float* Wk = (const float*)d_in[3];
    const float* bk = (const float*)d_in[4];
    const float* Wv = (const float*)d_in[5];
    const float* bv = (const float*)d_in[6];
    float* out = (float*)d_out;

    unsigned short* Xb = (unsigned short*)d_ws;
    unsigned short* Wb = Xb + (size_t)MROWS * DMODEL;
    unsigned short* Yb = Wb + (size_t)3 * DMODEL * DMODEL;

    cvt_all<<<2048 + 3 * 256, 256, 0, stream>>>(X, Wq, Wk, Wv, Xb, Wb);

    qkv_gemm<<<dim3(64, 8, 3), 256, 0, stream>>>(Xb, Wb, bq, bk, bv, Yb);

    const size_t hs = (size_t)MROWS * DMODEL;
    attn_fwd<<<1024, 256, 0, stream>>>(Yb, Yb + hs, Yb + 2 * hs, out);
}